// Round 3
// baseline (545.465 us; speedup 1.0000x reference)
//
#include <hip/hip_runtime.h>
#include <stdint.h>

// Workspace: [0,64MiB) h = coarse [b][cell][ic:32]; then 512KiB voxel bitmask.
#define H_BYTES ((size_t)2 * 262144 * 32 * sizeof(float))
#define MASK_WORDS (2 * 65536)

typedef float f32x4 __attribute__((ext_vector_type(4)));

__global__ __launch_bounds__(256) void scn_scatter_conv1(
    const float* __restrict__ feat, const float* __restrict__ W1,
    const int* __restrict__ coors, float* __restrict__ h,
    uint32_t* __restrict__ maskw, int npts)
{
    __shared__ float Ws[8 * 16 * 32];
    for (int i = threadIdx.x; i < 4096; i += 256) {
        // W1: [ic:32][cin:16][p:8] -> Ws[p][cin][ic]
        int ic = i >> 7, rem = i & 127, cin = rem >> 3, p = rem & 7;
        Ws[(p << 9) | (cin << 5) | ic] = W1[i];
    }
    __syncthreads();

    int total = npts * 32;
    for (int idx = blockIdx.x * 256 + threadIdx.x; idx < total;
         idx += gridDim.x * 256) {
        int pid = idx >> 5, ic = idx & 31;
        int b = coors[pid * 4 + 0];
        int z = coors[pid * 4 + 1];
        int y = coors[pid * 4 + 2];
        int x = coors[pid * 4 + 3];
        int p = ((z & 1) << 2) | ((y & 1) << 1) | (x & 1);

        const f32x4* f4 = reinterpret_cast<const f32x4*>(feat + pid * 16);
        f32x4 a0 = f4[0], a1 = f4[1], a2 = f4[2], a3 = f4[3];

        const float* w = Ws + (p << 9) + ic;   // stride 32 over cin
        float s = 0.f;
        s += a0[0] * w[0 << 5];   s += a0[1] * w[1 << 5];
        s += a0[2] * w[2 << 5];   s += a0[3] * w[3 << 5];
        s += a1[0] * w[4 << 5];   s += a1[1] * w[5 << 5];
        s += a1[2] * w[6 << 5];   s += a1[3] * w[7 << 5];
        s += a2[0] * w[8 << 5];   s += a2[1] * w[9 << 5];
        s += a2[2] * w[10 << 5];  s += a2[3] * w[11 << 5];
        s += a3[0] * w[12 << 5];  s += a3[1] * w[13 << 5];
        s += a3[2] * w[14 << 5];  s += a3[3] * w[15 << 5];

        int cell = (b << 18) | ((z >> 1) << 12) | ((y >> 1) << 6) | (x >> 1);
        atomicAdd(&h[((size_t)cell << 5) | ic], s);

        if (ic == 0) {
            int voxel = (z << 14) | (y << 7) | x;
            atomicOr(&maskw[(b << 16) | (voxel >> 5)], 1u << (voxel & 31));
        }
    }
}

// Fused zero-fill + deconv gather: out[b][oc:16][z][y][x] written exactly once.
// dec[b,oc,z,y,x] = sum_ic h[b,ic,z>>1,y>>1,x>>1] * W2tap((z&1)^1,(y&1)^1,(x&1)^1)
__global__ __launch_bounds__(256) void scn_fill_deconv(
    const float* __restrict__ h, const float* __restrict__ W2,
    const uint32_t* __restrict__ maskw, float* __restrict__ out)
{
    __shared__ float Ws[8 * 32 * 16];
    for (int i = threadIdx.x; i < 4096; i += 256) {
        // W2: [oc:16][ic:32][p:8] -> Ws[p][ic][oc]   (round-1 validated decode)
        int oc = i >> 8, rem = i & 255, ic = rem >> 3, p = rem & 7;
        Ws[(p << 9) | (ic << 4) | oc] = W2[i];
    }
    __syncthreads();

    const int total4 = 16777216;          // 2*16*128^3 / 4
    f32x4* out4 = reinterpret_cast<f32x4*>(out);
    for (int o = blockIdx.x * 256 + threadIdx.x; o < total4;
         o += gridDim.x * 256) {
        int voxel4 = o & 524287;          // float4 index within one image
        int chan   = o >> 19;             // b*16 + oc
        int b = chan >> 4;
        uint32_t mword = maskw[(b << 16) | (voxel4 >> 3)];
        uint32_t nib = (mword >> ((voxel4 & 7) << 2)) & 0xFu;

        f32x4 r = {0.f, 0.f, 0.f, 0.f};
        if (nib) {
            int oc = chan & 15;
            int x4 = voxel4 & 31;
            int y  = (voxel4 >> 5) & 127;
            int z  = voxel4 >> 12;
            int cellzy = (b << 18) | ((z >> 1) << 12) | ((y >> 1) << 6);
            int pzy = (((z & 1) ^ 1) << 2) | (((y & 1) ^ 1) << 1);
            #pragma unroll
            for (int j = 0; j < 4; ++j) {
                if ((nib >> j) & 1u) {
                    int x = (x4 << 2) | j;
                    int p = pzy | ((x & 1) ^ 1);
                    int cell = cellzy | (x >> 1);
                    const f32x4* hc =
                        reinterpret_cast<const f32x4*>(h + ((size_t)cell << 5));
                    const float* w = Ws + (p << 9) + oc;  // stride 16 over ic
                    float s = 0.f;
                    #pragma unroll
                    for (int q = 0; q < 8; ++q) {
                        f32x4 hv = hc[q];
                        s += hv[0] * w[(4 * q + 0) << 4];
                        s += hv[1] * w[(4 * q + 1) << 4];
                        s += hv[2] * w[(4 * q + 2) << 4];
                        s += hv[3] * w[(4 * q + 3) << 4];
                    }
                    r[j] = s;
                }
            }
        }
        __builtin_nontemporal_store(r, out4 + o);
    }
}

extern "C" void kernel_launch(void* const* d_in, const int* in_sizes, int n_in,
                              void* d_out, int out_size, void* d_ws, size_t ws_size,
                              hipStream_t stream) {
    const float* feat  = (const float*)d_in[0];
    const float* W1    = (const float*)d_in[1];
    const float* W2    = (const float*)d_in[2];
    const int*   coors = (const int*)d_in[3];
    float*       out   = (float*)d_out;
    float*       h     = (float*)d_ws;
    uint32_t*    maskw = (uint32_t*)((char*)d_ws + H_BYTES);
    int npts = in_sizes[0] / 16;

    // h must start at zero for the atomic scatter; mask likewise.
    hipMemsetAsync(d_ws, 0, H_BYTES + MASK_WORDS * sizeof(uint32_t), stream);

    int t1 = npts * 32;
    int blocks1 = (t1 + 255) / 256;
    if (blocks1 > 4096) blocks1 = 4096;
    scn_scatter_conv1<<<blocks1, 256, 0, stream>>>(feat, W1, coors, h, maskw, npts);

    scn_fill_deconv<<<8192, 256, 0, stream>>>(h, W2, maskw, out);
}

// Round 7
// 436.291 us; speedup vs baseline: 1.2502x; 1.2502x over previous
//
#include <hip/hip_runtime.h>
#include <stdint.h>

// Workspace layout (bytes):
//   [0, 64Mi)            h: coarse activations [b][cell][ic:32]
//   [64Mi, +512Ki)       maskw: 1 bit per fine voxel, word = (b<<16)|(voxel>>5)
//   [+4B @ CNT_OFF]      counter (compact voxel count)
//   [BASE_OFF, +512Ki)   basew: per-mask-word exclusive base index into wl/vals
//   [WL_OFF, +1Mi)       wl: compact voxel ids (b<<21|z<<14|y<<7|x)
//   [VALS_OFF, +16Mi)    vals: [oc:16][PITCH] precomputed deconv outputs
#define H_BYTES   ((size_t)67108864)
#define MASK_OFF  ((size_t)67108864)
#define CNT_OFF   ((size_t)67633152)
#define BASE_OFF  ((size_t)67633408)
#define WL_OFF    ((size_t)68157696)
#define VALS_OFF  ((size_t)69206272)
#define PITCH     262144
#define NWORDS    131072

typedef float f32x4 __attribute__((ext_vector_type(4)));

__global__ __launch_bounds__(256) void scn_scatter_conv1(
    const float* __restrict__ feat, const float* __restrict__ W1,
    const int* __restrict__ coors, float* __restrict__ h,
    uint32_t* __restrict__ maskw, int npts)
{
    __shared__ float Ws[8 * 16 * 32];
    for (int i = threadIdx.x; i < 4096; i += 256) {
        // W1: [ic:32][cin:16][p:8] -> Ws[p][cin][ic]
        int ic = i >> 7, rem = i & 127, cin = rem >> 3, p = rem & 7;
        Ws[(p << 9) | (cin << 5) | ic] = W1[i];
    }
    __syncthreads();

    int total = npts * 32;
    for (int idx = blockIdx.x * 256 + threadIdx.x; idx < total;
         idx += gridDim.x * 256) {
        int pid = idx >> 5, ic = idx & 31;
        int b = coors[pid * 4 + 0];
        int z = coors[pid * 4 + 1];
        int y = coors[pid * 4 + 2];
        int x = coors[pid * 4 + 3];
        int p = ((z & 1) << 2) | ((y & 1) << 1) | (x & 1);

        const f32x4* f4 = reinterpret_cast<const f32x4*>(feat + pid * 16);
        f32x4 a0 = f4[0], a1 = f4[1], a2 = f4[2], a3 = f4[3];

        const float* w = Ws + (p << 9) + ic;   // stride 32 over cin
        float s = 0.f;
        s += a0[0] * w[0 << 5];   s += a0[1] * w[1 << 5];
        s += a0[2] * w[2 << 5];   s += a0[3] * w[3 << 5];
        s += a1[0] * w[4 << 5];   s += a1[1] * w[5 << 5];
        s += a1[2] * w[6 << 5];   s += a1[3] * w[7 << 5];
        s += a2[0] * w[8 << 5];   s += a2[1] * w[9 << 5];
        s += a2[2] * w[10 << 5];  s += a2[3] * w[11 << 5];
        s += a3[0] * w[12 << 5];  s += a3[1] * w[13 << 5];
        s += a3[2] * w[14 << 5];  s += a3[3] * w[15 << 5];

        int cell = (b << 18) | ((z >> 1) << 12) | ((y >> 1) << 6) | (x >> 1);
        atomicAdd(&h[((size_t)cell << 5) | ic], s);

        if (ic == 0) {
            int voxel = (z << 14) | (y << 7) | x;
            atomicOr(&maskw[(b << 16) | (voxel >> 5)], 1u << (voxel & 31));
        }
    }
}

// Rank/select setup: per mask word, grab a base index and emit compact voxel ids.
__global__ __launch_bounds__(256) void scn_base_worklist(
    const uint32_t* __restrict__ maskw, uint32_t* __restrict__ basew,
    uint32_t* __restrict__ wl, uint32_t* __restrict__ cnt)
{
    int i = blockIdx.x * 256 + threadIdx.x;
    if (i >= NWORDS) return;
    uint32_t w = maskw[i];
    if (!w) return;
    int n = __popc(w);
    uint32_t b = atomicAdd(cnt, (uint32_t)n);
    basew[i] = b;
    uint32_t vbase = (uint32_t)i << 5;   // (b<<21)|(z<<14)|(y<<7)|(x&~31)
    while (w) {
        int bit = __ffs(w) - 1;
        wl[b++] = vbase | (uint32_t)bit;
        w &= w - 1;
    }
}

// Compute deconv outputs for compact voxels: vals[oc][i], coalesced over i.
__global__ __launch_bounds__(256) void scn_compute_vals(
    const float* __restrict__ h, const float* __restrict__ W2,
    const uint32_t* __restrict__ wl, const uint32_t* __restrict__ cnt,
    float* __restrict__ vals)
{
    // W2: [oc:16][ic:32][p:8] -> Ws[p*529 + ic*16 + oc]
    // plane stride 529: (529 mod 32)=17, p*17 mod 32 distinct for p=0..7 ->
    // the <=8 per-wave broadcast groups land in different banks.
    __shared__ float Ws[8 * 529];
    for (int i = threadIdx.x; i < 4096; i += 256) {
        int oc = i >> 8, rem = i & 255, ic = rem >> 3, p = rem & 7;
        Ws[p * 529 + (ic << 4) + oc] = W2[i];
    }
    __syncthreads();

    uint32_t n = *cnt;
    uint32_t t = blockIdx.x * 256 + threadIdx.x;   // t = oc*PITCH + i
    uint32_t i = t & (PITCH - 1);
    if (i >= n) return;
    int oc = t >> 18;

    uint32_t v = wl[i];
    int b = v >> 21, z = (v >> 14) & 127, y = (v >> 7) & 127, x = v & 127;
    int p = (((z & 1) ^ 1) << 2) | (((y & 1) ^ 1) << 1) | ((x & 1) ^ 1);
    int cell = (b << 18) | ((z >> 1) << 12) | ((y >> 1) << 6) | (x >> 1);

    const f32x4* hc = reinterpret_cast<const f32x4*>(h + ((size_t)cell << 5));
    const float* w = Ws + p * 529 + oc;   // stride 16 over ic
    float s = 0.f;
    #pragma unroll
    for (int q = 0; q < 8; ++q) {
        f32x4 hv = hc[q];
        s += hv[0] * w[(4 * q + 0) << 4];
        s += hv[1] * w[(4 * q + 1) << 4];
        s += hv[2] * w[(4 * q + 2) << 4];
        s += hv[3] * w[(4 * q + 3) << 4];
    }
    vals[(size_t)oc * PITCH + i] = s;
}

// Streaming fill: every output float4 written exactly once; occupied voxels
// pull their precomputed value via bitmap rank lookup (no FMAs, no LDS).
__global__ __launch_bounds__(256) void scn_fill_merge(
    const uint32_t* __restrict__ maskw, const uint32_t* __restrict__ basew,
    const float* __restrict__ vals, float* __restrict__ out)
{
    int o = blockIdx.x * 256 + threadIdx.x;     // float4 index, 16M total
    int voxel4 = o & 524287;                    // within one image
    int chan   = o >> 19;                       // b*16 + oc
    int b = chan >> 4;
    int word = (b << 16) | (voxel4 >> 3);
    uint32_t mword = maskw[word];
    uint32_t nib = (mword >> ((voxel4 & 7) << 2)) & 0xFu;

    f32x4 r = {0.f, 0.f, 0.f, 0.f};
    if (nib) {
        const float* voc = vals + ((size_t)(chan & 15) << 18);
        uint32_t base = basew[word];
        int bit0 = (voxel4 & 7) << 2;
        #pragma unroll
        for (int j = 0; j < 4; ++j) {
            if ((nib >> j) & 1u) {
                uint32_t rank = __popc(mword & ((1u << (bit0 + j)) - 1u));
                r[j] = voc[base + rank];
            }
        }
    }
    __builtin_nontemporal_store(r, reinterpret_cast<f32x4*>(out) + o);
}

extern "C" void kernel_launch(void* const* d_in, const int* in_sizes, int n_in,
                              void* d_out, int out_size, void* d_ws, size_t ws_size,
                              hipStream_t stream) {
    const float* feat  = (const float*)d_in[0];
    const float* W1    = (const float*)d_in[1];
    const float* W2    = (const float*)d_in[2];
    const int*   coors = (const int*)d_in[3];
    float*       out   = (float*)d_out;

    char* ws = (char*)d_ws;
    float*    h     = (float*)ws;
    uint32_t* maskw = (uint32_t*)(ws + MASK_OFF);
    uint32_t* cnt   = (uint32_t*)(ws + CNT_OFF);
    uint32_t* basew = (uint32_t*)(ws + BASE_OFF);
    uint32_t* wl    = (uint32_t*)(ws + WL_OFF);
    float*    vals  = (float*)(ws + VALS_OFF);
    int npts = in_sizes[0] / 16;

    // Zero h + maskw + counter (basew/wl/vals fully written before any read).
    hipMemsetAsync(d_ws, 0, CNT_OFF + 256, stream);

    int t1 = npts * 32;
    int blocks1 = (t1 + 255) / 256;
    if (blocks1 > 4096) blocks1 = 4096;
    scn_scatter_conv1<<<blocks1, 256, 0, stream>>>(feat, W1, coors, h, maskw, npts);

    scn_base_worklist<<<NWORDS / 256, 256, 0, stream>>>(maskw, basew, wl, cnt);

    scn_compute_vals<<<16 * PITCH / 256, 256, 0, stream>>>(h, W2, wl, cnt, vals);

    scn_fill_merge<<<16777216 / 256, 256, 0, stream>>>(maskw, basew, vals, out);
}

// Round 9
// 392.802 us; speedup vs baseline: 1.3886x; 1.1107x over previous
//
#include <hip/hip_runtime.h>
#include <stdint.h>

// Workspace layout (bytes):
//   [0, 64Mi)            h: coarse activations [b][cell][ic:32]
//   [64Mi, +512Ki)       maskw: 1 bit per fine voxel, word = (b<<16)|(voxel>>5)
//   [+4B @ CNT_OFF]      counter (compact voxel count)
//   [BASE_OFF, +512Ki)   basew: per-mask-word exclusive base index into wl/vals
//   [WL_OFF, +1Mi)       wl: compact voxel ids (b<<21|z<<14|y<<7|x)
//   [VALS_OFF, +16Mi)    vals: [oc:16][PITCH] precomputed deconv outputs
#define H_BYTES   ((size_t)67108864)
#define MASK_OFF  ((size_t)67108864)
#define CNT_OFF   ((size_t)67633152)
#define BASE_OFF  ((size_t)67633408)
#define WL_OFF    ((size_t)68157696)
#define VALS_OFF  ((size_t)69206272)
#define PITCH     262144
#define NWORDS    131072

typedef float f32x4 __attribute__((ext_vector_type(4)));

__global__ __launch_bounds__(256) void scn_scatter_conv1(
    const float* __restrict__ feat, const float* __restrict__ W1,
    const int* __restrict__ coors, float* __restrict__ h,
    uint32_t* __restrict__ maskw, int npts)
{
    __shared__ float Ws[8 * 16 * 32];
    for (int i = threadIdx.x; i < 4096; i += 256) {
        // W1: [ic:32][cin:16][p:8] -> Ws[p][cin][ic]
        int ic = i >> 7, rem = i & 127, cin = rem >> 3, p = rem & 7;
        Ws[(p << 9) | (cin << 5) | ic] = W1[i];
    }
    __syncthreads();

    int total = npts * 32;
    for (int idx = blockIdx.x * 256 + threadIdx.x; idx < total;
         idx += gridDim.x * 256) {
        int pid = idx >> 5, ic = idx & 31;
        int b = coors[pid * 4 + 0];
        int z = coors[pid * 4 + 1];
        int y = coors[pid * 4 + 2];
        int x = coors[pid * 4 + 3];
        int p = ((z & 1) << 2) | ((y & 1) << 1) | (x & 1);

        const f32x4* f4 = reinterpret_cast<const f32x4*>(feat + pid * 16);
        f32x4 a0 = f4[0], a1 = f4[1], a2 = f4[2], a3 = f4[3];

        const float* w = Ws + (p << 9) + ic;   // stride 32 over cin
        float s = 0.f;
        s += a0[0] * w[0 << 5];   s += a0[1] * w[1 << 5];
        s += a0[2] * w[2 << 5];   s += a0[3] * w[3 << 5];
        s += a1[0] * w[4 << 5];   s += a1[1] * w[5 << 5];
        s += a1[2] * w[6 << 5];   s += a1[3] * w[7 << 5];
        s += a2[0] * w[8 << 5];   s += a2[1] * w[9 << 5];
        s += a2[2] * w[10 << 5];  s += a2[3] * w[11 << 5];
        s += a3[0] * w[12 << 5];  s += a3[1] * w[13 << 5];
        s += a3[2] * w[14 << 5];  s += a3[3] * w[15 << 5];

        int cell = (b << 18) | ((z >> 1) << 12) | ((y >> 1) << 6) | (x >> 1);
        atomicAdd(&h[((size_t)cell << 5) | ic], s);

        if (ic == 0) {
            int voxel = (z << 14) | (y << 7) | x;
            atomicOr(&maskw[(b << 16) | (voxel >> 5)], 1u << (voxel & 31));
        }
    }
}

// Rank/select setup: per mask word, grab a base index and emit compact voxel ids.
__global__ __launch_bounds__(256) void scn_base_worklist(
    const uint32_t* __restrict__ maskw, uint32_t* __restrict__ basew,
    uint32_t* __restrict__ wl, uint32_t* __restrict__ cnt)
{
    int i = blockIdx.x * 256 + threadIdx.x;
    if (i >= NWORDS) return;
    uint32_t w = maskw[i];
    if (!w) return;
    int n = __popc(w);
    uint32_t b = atomicAdd(cnt, (uint32_t)n);
    basew[i] = b;
    uint32_t vbase = (uint32_t)i << 5;   // (b<<21)|(z<<14)|(y<<7)|(x&~31)
    while (w) {
        int bit = __ffs(w) - 1;
        wl[b++] = vbase | (uint32_t)bit;
        w &= w - 1;
    }
}

// One thread per compact voxel: load h[cell] ONCE (128 B), compute all 16 oc.
__global__ __launch_bounds__(256) void scn_compute_vals(
    const float* __restrict__ h, const float* __restrict__ W2,
    const uint32_t* __restrict__ wl, const uint32_t* __restrict__ cnt,
    float* __restrict__ vals)
{
    // W2: [oc:16][ic:32][p:8] -> Ws[p*529 + ic*16 + oc]
    // plane stride 529: (529 mod 32)=17 -> p*17 mod 32 distinct for p=0..7,
    // so the 8 per-wave broadcast groups land in 8 distinct banks.
    __shared__ float Ws[8 * 529];
    for (int i = threadIdx.x; i < 4096; i += 256) {
        int oc = i >> 8, rem = i & 255, ic = rem >> 3, p = rem & 7;
        Ws[p * 529 + (ic << 4) + oc] = W2[i];
    }
    __syncthreads();

    uint32_t n = *cnt;
    uint32_t i = blockIdx.x * 256 + threadIdx.x;
    if (i >= n) return;

    uint32_t v = wl[i];
    int b = v >> 21, z = (v >> 14) & 127, y = (v >> 7) & 127, x = v & 127;
    int p = (((z & 1) ^ 1) << 2) | (((y & 1) ^ 1) << 1) | ((x & 1) ^ 1);
    int cell = (b << 18) | ((z >> 1) << 12) | ((y >> 1) << 6) | (x >> 1);

    const f32x4* hc = reinterpret_cast<const f32x4*>(h + ((size_t)cell << 5));
    f32x4 hv[8];
    #pragma unroll
    for (int q = 0; q < 8; ++q) hv[q] = hc[q];

    const float* wp = Ws + p * 529;
    for (int oc = 0; oc < 16; ++oc) {
        float s = 0.f;
        #pragma unroll
        for (int q = 0; q < 8; ++q) {
            s += hv[q][0] * wp[((4 * q + 0) << 4) + oc];
            s += hv[q][1] * wp[((4 * q + 1) << 4) + oc];
            s += hv[q][2] * wp[((4 * q + 2) << 4) + oc];
            s += hv[q][3] * wp[((4 * q + 3) << 4) + oc];
        }
        vals[(size_t)oc * PITCH + i] = s;
    }
}

// Streaming fill: grid-stride, 32 float4s per thread; every output float4
// written exactly once; occupied voxels pull their value via bitmap rank.
__global__ __launch_bounds__(256) void scn_fill_merge(
    const uint32_t* __restrict__ maskw, const uint32_t* __restrict__ basew,
    const float* __restrict__ vals, float* __restrict__ out)
{
    const int total4 = 16777216;                // 2*16*128^3 / 4
    int stride = gridDim.x * 256;
    for (int o = blockIdx.x * 256 + threadIdx.x; o < total4; o += stride) {
        int voxel4 = o & 524287;                // float4 index within one image
        int chan   = o >> 19;                   // b*16 + oc
        int b = chan >> 4;
        int word = (b << 16) | (voxel4 >> 3);
        uint32_t mword = maskw[word];
        uint32_t nib = (mword >> ((voxel4 & 7) << 2)) & 0xFu;

        f32x4 r = {0.f, 0.f, 0.f, 0.f};
        if (nib) {
            const float* voc = vals + ((size_t)(chan & 15) << 18);
            uint32_t base = basew[word];
            int bit0 = (voxel4 & 7) << 2;
            #pragma unroll
            for (int j = 0; j < 4; ++j) {
                if ((nib >> j) & 1u) {
                    uint32_t rank = __popc(mword & ((1u << (bit0 + j)) - 1u));
                    r[j] = voc[base + rank];
                }
            }
        }
        __builtin_nontemporal_store(r, reinterpret_cast<f32x4*>(out) + o);
    }
}

extern "C" void kernel_launch(void* const* d_in, const int* in_sizes, int n_in,
                              void* d_out, int out_size, void* d_ws, size_t ws_size,
                              hipStream_t stream) {
    const float* feat  = (const float*)d_in[0];
    const float* W1    = (const float*)d_in[1];
    const float* W2    = (const float*)d_in[2];
    const int*   coors = (const int*)d_in[3];
    float*       out   = (float*)d_out;

    char* ws = (char*)d_ws;
    float*    h     = (float*)ws;
    uint32_t* maskw = (uint32_t*)(ws + MASK_OFF);
    uint32_t* cnt   = (uint32_t*)(ws + CNT_OFF);
    uint32_t* basew = (uint32_t*)(ws + BASE_OFF);
    uint32_t* wl    = (uint32_t*)(ws + WL_OFF);
    float*    vals  = (float*)(ws + VALS_OFF);
    int npts = in_sizes[0] / 16;

    // Zero h + maskw + counter (basew/wl/vals fully written before any read).
    hipMemsetAsync(d_ws, 0, CNT_OFF + 256, stream);

    int t1 = npts * 32;
    int blocks1 = (t1 + 255) / 256;
    if (blocks1 > 4096) blocks1 = 4096;
    scn_scatter_conv1<<<blocks1, 256, 0, stream>>>(feat, W1, coors, h, maskw, npts);

    scn_base_worklist<<<NWORDS / 256, 256, 0, stream>>>(maskw, basew, wl, cnt);

    // One thread per compact voxel (n <= npts <= 200k < 1024*256).
    scn_compute_vals<<<1024, 256, 0, stream>>>(h, W2, wl, cnt, vals);

    // Grid-stride streaming fill: 2048 blocks, 32 float4s per thread.
    scn_fill_merge<<<2048, 256, 0, stream>>>(maskw, basew, vals, out);
}